// Round 1
// baseline (567.157 us; speedup 1.0000x reference)
//
#include <hip/hip_runtime.h>
#include <cstdint>
#include <cstddef>

#define DIMX  1024
#define NH    8
#define HD    64
#define QKD   512            // NH*HD
#define VDD   128            // DIMX/NH
#define BATCH 4
#define SEQ   1024
#define NPOS  (BATCH*SEQ)    // 4096
#define TW    (2*QKD + DIMX) // 2048
#define SCALE 0.125f         // HD^-0.5

// ---------------------------------------------------------------------------
// Generic fp32 GEMM: C[M,N] = A[M,K] @ B[K,N], all row-major.
// 64x64 tile, BK=32, 256 threads, 4x4 microtile per thread.
// ---------------------------------------------------------------------------
__global__ __launch_bounds__(256, 4)
void gemm_f32_64x64(const float* __restrict__ A, const float* __restrict__ B,
                    float* __restrict__ C, int M, int N, int K)
{
    __shared__ float Ast[32][68];   // [kk][row], padded
    __shared__ float Bs [32][68];   // [kk][col], padded

    const int tid = threadIdx.x;
    const int bm  = blockIdx.y * 64;
    const int bn  = blockIdx.x * 64;
    const int i0  = (tid >> 4) * 4;   // 0..60
    const int j0  = (tid & 15) * 4;   // 0..60

    const int ar = tid >> 2;          // 0..63
    const int ac = (tid & 3) * 8;     // 0,8,16,24
    const int br = tid >> 3;          // 0..31
    const int bc = (tid & 7) * 8;     // 0..56

    const float* Ap = A + (size_t)(bm + ar) * K + ac;
    const float* Bp = B + (size_t)br * N + bn + bc;

    float acc[4][4] = {};

    for (int k0 = 0; k0 < K; k0 += 32) {
        float4 a0 = *(const float4*)(Ap);
        float4 a1 = *(const float4*)(Ap + 4);
        float4 b0 = *(const float4*)(Bp);
        float4 b1 = *(const float4*)(Bp + 4);
        __syncthreads();               // prev iter LDS reads complete
        Ast[ac+0][ar] = a0.x; Ast[ac+1][ar] = a0.y;
        Ast[ac+2][ar] = a0.z; Ast[ac+3][ar] = a0.w;
        Ast[ac+4][ar] = a1.x; Ast[ac+5][ar] = a1.y;
        Ast[ac+6][ar] = a1.z; Ast[ac+7][ar] = a1.w;
        *(float4*)&Bs[br][bc]     = b0;
        *(float4*)&Bs[br][bc + 4] = b1;
        __syncthreads();
        #pragma unroll
        for (int kk = 0; kk < 32; ++kk) {
            const float4 av = *(const float4*)&Ast[kk][i0];
            const float4 bv = *(const float4*)&Bs[kk][j0];
            const float a4[4] = {av.x, av.y, av.z, av.w};
            const float b4[4] = {bv.x, bv.y, bv.z, bv.w};
            #pragma unroll
            for (int r = 0; r < 4; ++r)
                #pragma unroll
                for (int c = 0; c < 4; ++c)
                    acc[r][c] = fmaf(a4[r], b4[c], acc[r][c]);
        }
        Ap += 32;
        Bp += (size_t)32 * N;
    }

    #pragma unroll
    for (int r = 0; r < 4; ++r) {
        float4 v = make_float4(acc[r][0], acc[r][1], acc[r][2], acc[r][3]);
        *(float4*)&C[(size_t)(bm + i0 + r) * N + bn + j0] = v;
    }
}

// ---------------------------------------------------------------------------
// In-place masked rotation of q,k inside t = [NPOS, TW].
// q' = R q ; k' = R^T k  (only where mask != 0). One block per position.
// ---------------------------------------------------------------------------
__global__ __launch_bounds__(256)
void rotate_qk(float* __restrict__ t, const int* __restrict__ mask,
               const float* __restrict__ rot)
{
    const int p   = blockIdx.x;       // 0..NPOS-1
    const int tid = threadIdx.x;
    if (mask[p] == 0) return;         // block-uniform

    __shared__ float R[64][69];       // odd pad: conflict-free row & col reads
    __shared__ float qv[QKD];
    __shared__ float kv[QKD];

    float* tq = t + (size_t)p * TW;   // q at 0, k at QKD

    {
        const float* Rg = rot + (size_t)p * 4096;
        const int base = tid * 16;
        const int r = base >> 6, c = base & 63;
        #pragma unroll
        for (int x = 0; x < 16; x += 4) {
            float4 v = *(const float4*)(Rg + base + x);
            R[r][c+x+0] = v.x; R[r][c+x+1] = v.y;
            R[r][c+x+2] = v.z; R[r][c+x+3] = v.w;
        }
        float2 q2 = *(const float2*)(tq + tid*2);
        float2 k2 = *(const float2*)(tq + QKD + tid*2);
        qv[tid*2]   = q2.x; qv[tid*2+1] = q2.y;
        kv[tid*2]   = k2.x; kv[tid*2+1] = k2.y;
    }
    __syncthreads();

    #pragma unroll
    for (int ph = 0; ph < 2; ++ph) {
        const int h = (tid >> 6) + ph*4;   // head
        const int i = tid & 63;            // output index within head
        const float* qh = &qv[h*64];
        const float* kh = &kv[h*64];
        float aq = 0.f, ak = 0.f;
        #pragma unroll 8
        for (int j = 0; j < 64; ++j) {
            aq = fmaf(R[i][j], qh[j], aq);   // (R q)_i
            ak = fmaf(R[j][i], kh[j], ak);   // (R^T k)_i
        }
        tq[h*64 + i]       = aq;
        tq[QKD + h*64 + i] = ak;
    }
}

// ---------------------------------------------------------------------------
// Fused Taylor attention. One block = (b, h, 64 q-rows). 256 threads.
// Thread (rg,cg): rg=tid>>4 owns q-rows rg*4..rg*4+3; cg=tid&15.
// stage1: S[4x4] cols cg*4.., stage2: out[4 rows x 8 cols] cols cg*8..
// ---------------------------------------------------------------------------
__global__ __launch_bounds__(256, 2)
void taylor_attn(const float* __restrict__ t, const int* __restrict__ mask,
                 float* __restrict__ attn)
{
    const int bh  = blockIdx.x;        // b*NH + h
    const int qt  = blockIdx.y;        // 0..15
    const int b   = bh >> 3, h = bh & 7;
    const int tid = threadIdx.x;
    const int rg  = tid >> 4;          // 0..15
    const int cg  = tid & 15;          // 0..15

    __shared__ float Qs[64][68];       // q-tile, padded for float4 stores
    __shared__ float Ss[64][65];       // scores tile
    __shared__ float KV[64*128];       // union: K uses [j*65+jj], V uses [j*128+d]
    __shared__ float dred[64][16];
    __shared__ float mk[64];

    // load Q tile (rotated q lives in t[:, 0:QKD])
    {
        const int r = tid >> 2, c = (tid & 3) * 16;
        const float* src = t + (size_t)(b*SEQ + qt*64 + r) * TW + h*HD + c;
        #pragma unroll
        for (int x = 0; x < 16; x += 4)
            *(float4*)&Qs[r][c+x] = *(const float4*)(src + x);
    }

    float acc[4][8] = {};
    float dsum[4]   = {};

    for (int kt = 0; kt < 16; ++kt) {
        __syncthreads();   // prev stage2 done: KV and Ss reusable
        // ---- load K tile (padded 65) + mask tile ----
        {
            const int r = tid >> 2, c = (tid & 3) * 16;
            const float* src = t + (size_t)(b*SEQ + kt*64 + r) * TW + QKD + h*HD + c;
            #pragma unroll
            for (int x = 0; x < 16; x += 4) {
                float4 v = *(const float4*)(src + x);
                KV[r*65 + c + x + 0] = v.x; KV[r*65 + c + x + 1] = v.y;
                KV[r*65 + c + x + 2] = v.z; KV[r*65 + c + x + 3] = v.w;
            }
        }
        if (tid < 64) mk[tid] = (mask[b*SEQ + kt*64 + tid] != 0) ? 1.f : 0.f;
        __syncthreads();
        // ---- stage1: S = (Q K^T)*scale -> taylor scores ----
        {
            float sacc[4][4] = {};
            #pragma unroll 2
            for (int jj = 0; jj < 64; jj += 4) {
                float4 qv4[4], kv4[4];
                #pragma unroll
                for (int r = 0; r < 4; ++r)
                    qv4[r] = *(const float4*)&Qs[rg*4 + r][jj];
                #pragma unroll
                for (int c = 0; c < 4; ++c)
                    kv4[c] = *(const float4*)&KV[(cg*4 + c)*65 + jj];
                #pragma unroll
                for (int r = 0; r < 4; ++r)
                    #pragma unroll
                    for (int c = 0; c < 4; ++c)
                        sacc[r][c] += qv4[r].x*kv4[c].x + qv4[r].y*kv4[c].y
                                    + qv4[r].z*kv4[c].z + qv4[r].w*kv4[c].w;
            }
            #pragma unroll
            for (int r = 0; r < 4; ++r)
                #pragma unroll
                for (int c = 0; c < 4; ++c) {
                    const float s  = sacc[r][c] * SCALE;
                    const float sc = (1.f + s + 0.5f*s*s) * mk[cg*4 + c];
                    dsum[r] += sc;
                    Ss[rg*4 + r][cg*4 + c] = sc;
                }
        }
        __syncthreads();
        // ---- load V tile (overwrites K region; linear float4, conflict-free) ----
        {
            #pragma unroll
            for (int w = 0; w < 8; ++w) {
                const int idx = (tid + w*256) * 4;      // float index in [0,8192)
                const int r = idx >> 7, c = idx & 127;
                float4 v = *(const float4*)(t + (size_t)(b*SEQ + kt*64 + r)*TW
                                            + 2*QKD + h*VDD + c);
                *(float4*)&KV[idx] = v;
            }
        }
        __syncthreads();
        // ---- stage2: out += S @ V ----
        {
            #pragma unroll 4
            for (int j = 0; j < 64; ++j) {
                float sv[4];
                #pragma unroll
                for (int r = 0; r < 4; ++r) sv[r] = Ss[rg*4 + r][j];
                const float4 v0 = *(const float4*)&KV[j*128 + cg*8];
                const float4 v1 = *(const float4*)&KV[j*128 + cg*8 + 4];
                #pragma unroll
                for (int r = 0; r < 4; ++r) {
                    acc[r][0] = fmaf(sv[r], v0.x, acc[r][0]);
                    acc[r][1] = fmaf(sv[r], v0.y, acc[r][1]);
                    acc[r][2] = fmaf(sv[r], v0.z, acc[r][2]);
                    acc[r][3] = fmaf(sv[r], v0.w, acc[r][3]);
                    acc[r][4] = fmaf(sv[r], v1.x, acc[r][4]);
                    acc[r][5] = fmaf(sv[r], v1.y, acc[r][5]);
                    acc[r][6] = fmaf(sv[r], v1.z, acc[r][6]);
                    acc[r][7] = fmaf(sv[r], v1.w, acc[r][7]);
                }
            }
        }
    }

    // ---- denom reduce across the 16 col-groups, normalize, write ----
    #pragma unroll
    for (int r = 0; r < 4; ++r) dred[rg*4 + r][cg] = dsum[r];
    __syncthreads();
    #pragma unroll
    for (int r = 0; r < 4; ++r) {
        float d = 0.f;
        #pragma unroll
        for (int g = 0; g < 16; ++g) d += dred[rg*4 + r][g];
        d = fmaxf(d, 1e-6f);
        const float inv = 1.f / d;
        float4 o0 = make_float4(acc[r][0]*inv, acc[r][1]*inv, acc[r][2]*inv, acc[r][3]*inv);
        float4 o1 = make_float4(acc[r][4]*inv, acc[r][5]*inv, acc[r][6]*inv, acc[r][7]*inv);
        float* dst = attn + (size_t)(b*SEQ + qt*64 + rg*4 + r) * DIMX + h*VDD + cg*8;
        *(float4*)(dst)     = o0;
        *(float4*)(dst + 4) = o1;
    }
}

// ---------------------------------------------------------------------------
extern "C" void kernel_launch(void* const* d_in, const int* in_sizes, int n_in,
                              void* d_out, int out_size, void* d_ws, size_t ws_size,
                              hipStream_t stream)
{
    const float* x    = (const float*)d_in[0];
    const int*   mask = (const int*)d_in[1];
    const float* rot  = (const float*)d_in[2];
    const float* w_t  = (const float*)d_in[3];
    const float* w_o  = (const float*)d_in[4];
    float* out = (float*)d_out;

    float* t    = (float*)d_ws;                    // [NPOS, TW]   32 MB
    float* attn = t + (size_t)NPOS * TW;           // [NPOS, DIMX] 16 MB

    // 1) t = x @ w_t
    gemm_f32_64x64<<<dim3(TW/64, NPOS/64), 256, 0, stream>>>(x, w_t, t, NPOS, TW, DIMX);
    // 2) rotate q,k in place (masked)
    rotate_qk<<<NPOS, 256, 0, stream>>>(t, mask, rot);
    // 3) fused Taylor attention -> attn [NPOS, DIMX]
    taylor_attn<<<dim3(BATCH*NH, SEQ/64), 256, 0, stream>>>(t, mask, attn);
    // 4) out = attn @ w_o
    gemm_f32_64x64<<<dim3(DIMX/64, NPOS/64), 256, 0, stream>>>(attn, w_o, out, NPOS, DIMX, DIMX);
}

// Round 2
// 283.419 us; speedup vs baseline: 2.0011x; 2.0011x over previous
//
#include <hip/hip_runtime.h>
#include <cstdint>
#include <cstddef>

#define DIMX  1024
#define NH    8
#define HD    64
#define QKD   512            // NH*HD
#define VDD   128            // DIMX/NH
#define BATCH 4
#define SEQ   1024
#define NPOS  (BATCH*SEQ)    // 4096
#define TW    (2*QKD + DIMX) // 2048
#define SCALE 0.125f         // HD^-0.5

typedef __bf16 bf16x8 __attribute__((ext_vector_type(8)));
typedef float  f32x4  __attribute__((ext_vector_type(4)));

__device__ __forceinline__ ushort f2bf(float f) {
    unsigned b = __float_as_uint(f);
    return (ushort)((b + 0x7FFFu + ((b >> 16) & 1u)) >> 16);   // RNE, finite data
}

#define GLD16(src, dst) __builtin_amdgcn_global_load_lds(                      \
    (const __attribute__((address_space(1))) unsigned int*)(src),              \
    (__attribute__((address_space(3))) unsigned int*)(dst), 16, 0, 0)

// ---------------------------------------------------------------------------
// fp32 -> bf16 cast (same layout). n4 = elem_count/4.
// ---------------------------------------------------------------------------
__global__ __launch_bounds__(256)
void cast_bf16(const float* __restrict__ in, ushort* __restrict__ out, int n4)
{
    const int i = blockIdx.x * 256 + threadIdx.x;
    if (i >= n4) return;
    float4 v = *(const float4*)(in + (size_t)i * 4);
    ushort4 o;
    o.x = f2bf(v.x); o.y = f2bf(v.y); o.z = f2bf(v.z); o.w = f2bf(v.w);
    *(ushort4*)(out + (size_t)i * 4) = o;
}

// ---------------------------------------------------------------------------
// W[K][N] fp32 -> WT[N][K] bf16 (transpose + cast). 32x32 tiles.
// ---------------------------------------------------------------------------
__global__ __launch_bounds__(256)
void transpose_cast(const float* __restrict__ W, ushort* __restrict__ WT,
                    int K, int N)
{
    __shared__ float tile[32][33];
    const int bn = blockIdx.x * 32;
    const int bk = blockIdx.y * 32;
    const int tx = threadIdx.x & 31;
    const int ty = threadIdx.x >> 5;      // 0..7
    #pragma unroll
    for (int i = ty; i < 32; i += 8)
        tile[i][tx] = W[(size_t)(bk + i) * N + bn + tx];
    __syncthreads();
    #pragma unroll
    for (int i = ty; i < 32; i += 8)
        WT[(size_t)(bn + i) * K + bk + tx] = f2bf(tile[tx][i]);
}

// ---------------------------------------------------------------------------
// bf16 MFMA GEMM: C[M][N] fp32 = A[M][K] * BT[N][K]^T (both bf16).
// 128x128 tile, BK=32, 256 threads = 4 waves (2x2), 4x4 frags of 16x16x32.
// m97-style 2-barrier loop, global_load_lds width 16, linear LDS.
// ---------------------------------------------------------------------------
__global__ __launch_bounds__(256, 2)
void gemm_bf16_mfma(const ushort* __restrict__ A, const ushort* __restrict__ BT,
                    float* __restrict__ C, int M, int N, int K)
{
    __shared__ __align__(16) ushort lA[128 * 32];
    __shared__ __align__(16) ushort lB[128 * 32];

    const int tid  = threadIdx.x;
    const int lane = tid & 63;
    const int wave = tid >> 6;
    const int wr   = wave >> 1;           // 0..1
    const int wc   = wave & 1;            // 0..1
    const int bm   = blockIdx.y * 128;
    const int bn   = blockIdx.x * 128;

    // staging: chunk = wave*2+c covers LDS elems [chunk*512, +512) = 16 rows.
    // lane covers 8 elems at chunk*512 + lane*8 -> row = chunk*16 + lane/4,
    // kcol = (lane&3)*8. LDS dest base must be wave-uniform.
    const int r0 = wave * 32 + (lane >> 2);
    const int kc = (lane & 3) * 8;
    const ushort* a0 = A  + (size_t)(bm + r0) * K + kc;
    const ushort* a1 = A  + (size_t)(bm + r0 + 16) * K + kc;
    const ushort* b0 = BT + (size_t)(bn + r0) * K + kc;
    const ushort* b1 = BT + (size_t)(bn + r0 + 16) * K + kc;
    ushort* lA0 = lA + wave * 1024;
    ushort* lA1 = lA0 + 512;
    ushort* lB0 = lB + wave * 1024;
    ushort* lB1 = lB0 + 512;

    // fragment read bases: A row = wr*64 + m*16 + (lane&15), k = (lane>>4)*8
    const int fr = lane & 15;
    const int kh = (lane >> 4) * 8;
    const ushort* ra = lA + (wr * 64 + fr) * 32 + kh;
    const ushort* rb = lB + (wc * 64 + fr) * 32 + kh;

    f32x4 acc[4][4] = {};

    for (int k0 = 0; k0 < K; k0 += 32) {
        GLD16(a0 + k0, lA0);
        GLD16(a1 + k0, lA1);
        GLD16(b0 + k0, lB0);
        GLD16(b1 + k0, lB1);
        asm volatile("s_waitcnt vmcnt(0)" ::: "memory");
        __syncthreads();                         // staged data visible
        bf16x8 af[4], bfr[4];
        #pragma unroll
        for (int m = 0; m < 4; ++m) af[m]  = *(const bf16x8*)(ra + m * 512);
        #pragma unroll
        for (int n = 0; n < 4; ++n) bfr[n] = *(const bf16x8*)(rb + n * 512);
        #pragma unroll
        for (int m = 0; m < 4; ++m)
            #pragma unroll
            for (int n = 0; n < 4; ++n)
                acc[m][n] = __builtin_amdgcn_mfma_f32_16x16x32_bf16(
                    af[m], bfr[n], acc[m][n], 0, 0, 0);
        __syncthreads();                         // reads done before next stage
    }

    // C/D layout: col = lane&15, row = (lane>>4)*4 + reg   [m89-verified]
    const int orow = (lane >> 4) * 4;
    #pragma unroll
    for (int m = 0; m < 4; ++m)
        #pragma unroll
        for (int n = 0; n < 4; ++n) {
            float* dst = C + (size_t)(bm + wr * 64 + m * 16 + orow) * N
                           + bn + wc * 64 + n * 16 + fr;
            #pragma unroll
            for (int q = 0; q < 4; ++q)
                dst[(size_t)q * N] = acc[m][n][q];
        }
}

// ---------------------------------------------------------------------------
// In-place masked rotation of q,k inside t = [NPOS, TW]. (fp32, unchanged)
// ---------------------------------------------------------------------------
__global__ __launch_bounds__(256)
void rotate_qk(float* __restrict__ t, const int* __restrict__ mask,
               const float* __restrict__ rot)
{
    const int p   = blockIdx.x;
    const int tid = threadIdx.x;
    if (mask[p] == 0) return;

    __shared__ float R[64][69];
    __shared__ float qv[QKD];
    __shared__ float kv[QKD];

    float* tq = t + (size_t)p * TW;

    {
        const float* Rg = rot + (size_t)p * 4096;
        const int base = tid * 16;
        const int r = base >> 6, c = base & 63;
        #pragma unroll
        for (int x = 0; x < 16; x += 4) {
            float4 v = *(const float4*)(Rg + base + x);
            R[r][c+x+0] = v.x; R[r][c+x+1] = v.y;
            R[r][c+x+2] = v.z; R[r][c+x+3] = v.w;
        }
        float2 q2 = *(const float2*)(tq + tid*2);
        float2 k2 = *(const float2*)(tq + QKD + tid*2);
        qv[tid*2]   = q2.x; qv[tid*2+1] = q2.y;
        kv[tid*2]   = k2.x; kv[tid*2+1] = k2.y;
    }
    __syncthreads();

    #pragma unroll
    for (int ph = 0; ph < 2; ++ph) {
        const int h = (tid >> 6) + ph*4;
        const int i = tid & 63;
        const float* qh = &qv[h*64];
        const float* kh2 = &kv[h*64];
        float aq = 0.f, ak = 0.f;
        #pragma unroll 8
        for (int j = 0; j < 64; ++j) {
            aq = fmaf(R[i][j], qh[j], aq);
            ak = fmaf(R[j][i], kh2[j], ak);
        }
        tq[h*64 + i]       = aq;
        tq[QKD + h*64 + i] = ak;
    }
}

// ---------------------------------------------------------------------------
// Fused Taylor attention (fp32 compute, bf16 output).
// ---------------------------------------------------------------------------
__global__ __launch_bounds__(256, 2)
void taylor_attn(const float* __restrict__ t, const int* __restrict__ mask,
                 ushort* __restrict__ attn)
{
    const int bh  = blockIdx.x;
    const int qt  = blockIdx.y;
    const int b   = bh >> 3, h = bh & 7;
    const int tid = threadIdx.x;
    const int rg  = tid >> 4;
    const int cg  = tid & 15;

    __shared__ float Qs[64][68];
    __shared__ float Ss[64][65];
    __shared__ float KV[64*128];
    __shared__ float dred[64][16];
    __shared__ float mk[64];

    {
        const int r = tid >> 2, c = (tid & 3) * 16;
        const float* src = t + (size_t)(b*SEQ + qt*64 + r) * TW + h*HD + c;
        #pragma unroll
        for (int x = 0; x < 16; x += 4)
            *(float4*)&Qs[r][c+x] = *(const float4*)(src + x);
    }

    float acc[4][8] = {};
    float dsum[4]   = {};

    for (int kt = 0; kt < 16; ++kt) {
        __syncthreads();
        {
            const int r = tid >> 2, c = (tid & 3) * 16;
            const float* src = t + (size_t)(b*SEQ + kt*64 + r) * TW + QKD + h*HD + c;
            #pragma unroll
            for (int x = 0; x < 16; x += 4) {
                float4 v = *(const float4*)(src + x);
                KV[r*65 + c + x + 0] = v.x; KV[r*65 + c + x + 1] = v.y;
                KV[r*65 + c + x + 2] = v.z; KV[r*65 + c + x + 3] = v.w;
            }
        }
        if (tid < 64) mk[tid] = (mask[b*SEQ + kt*64 + tid] != 0) ? 1.f : 0.f;
        __syncthreads();
        {
            float sacc[4][4] = {};
            #pragma unroll 2
            for (int jj = 0; jj < 64; jj += 4) {
                float4 qv4[4], kv4[4];
                #pragma unroll
                for (int r = 0; r < 4; ++r)
                    qv4[r] = *(const float4*)&Qs[rg*4 + r][jj];
                #pragma unroll
                for (int c = 0; c < 4; ++c)
                    kv4[c] = *(const float4*)&KV[(cg*4 + c)*65 + jj];
                #pragma unroll
                for (int r = 0; r < 4; ++r)
                    #pragma unroll
                    for (int c = 0; c < 4; ++c)
                        sacc[r][c] += qv4[r].x*kv4[c].x + qv4[r].y*kv4[c].y
                                    + qv4[r].z*kv4[c].z + qv4[r].w*kv4[c].w;
            }
            #pragma unroll
            for (int r = 0; r < 4; ++r)
                #pragma unroll
                for (int c = 0; c < 4; ++c) {
                    const float s  = sacc[r][c] * SCALE;
                    const float sc = (1.f + s + 0.5f*s*s) * mk[cg*4 + c];
                    dsum[r] += sc;
                    Ss[rg*4 + r][cg*4 + c] = sc;
                }
        }
        __syncthreads();
        {
            #pragma unroll
            for (int w = 0; w < 8; ++w) {
                const int idx = (tid + w*256) * 4;
                const int r = idx >> 7, c = idx & 127;
                float4 v = *(const float4*)(t + (size_t)(b*SEQ + kt*64 + r)*TW
                                            + 2*QKD + h*VDD + c);
                *(float4*)&KV[idx] = v;
            }
        }
        __syncthreads();
        {
            #pragma unroll 4
            for (int j = 0; j < 64; ++j) {
                float sv[4];
                #pragma unroll
                for (int r = 0; r < 4; ++r) sv[r] = Ss[rg*4 + r][j];
                const float4 v0 = *(const float4*)&KV[j*128 + cg*8];
                const float4 v1 = *(const float4*)&KV[j*128 + cg*8 + 4];
                #pragma unroll
                for (int r = 0; r < 4; ++r) {
                    acc[r][0] = fmaf(sv[r], v0.x, acc[r][0]);
                    acc[r][1] = fmaf(sv[r], v0.y, acc[r][1]);
                    acc[r][2] = fmaf(sv[r], v0.z, acc[r][2]);
                    acc[r][3] = fmaf(sv[r], v0.w, acc[r][3]);
                    acc[r][4] = fmaf(sv[r], v1.x, acc[r][4]);
                    acc[r][5] = fmaf(sv[r], v1.y, acc[r][5]);
                    acc[r][6] = fmaf(sv[r], v1.z, acc[r][6]);
                    acc[r][7] = fmaf(sv[r], v1.w, acc[r][7]);
                }
            }
        }
    }

    #pragma unroll
    for (int r = 0; r < 4; ++r) dred[rg*4 + r][cg] = dsum[r];
    __syncthreads();
    #pragma unroll
    for (int r = 0; r < 4; ++r) {
        float d = 0.f;
        #pragma unroll
        for (int g = 0; g < 16; ++g) d += dred[rg*4 + r][g];
        d = fmaxf(d, 1e-6f);
        const float inv = 1.f / d;
        ushort ob[8];
        #pragma unroll
        for (int j = 0; j < 8; ++j) ob[j] = f2bf(acc[r][j] * inv);
        ushort* dst = attn + (size_t)(b*SEQ + qt*64 + rg*4 + r) * DIMX + h*VDD + cg*8;
        *(uint4*)dst = *(uint4*)ob;
    }
}

// ---------------------------------------------------------------------------
extern "C" void kernel_launch(void* const* d_in, const int* in_sizes, int n_in,
                              void* d_out, int out_size, void* d_ws, size_t ws_size,
                              hipStream_t stream)
{
    const float* x    = (const float*)d_in[0];
    const int*   mask = (const int*)d_in[1];
    const float* rot  = (const float*)d_in[2];
    const float* w_t  = (const float*)d_in[3];
    const float* w_o  = (const float*)d_in[4];
    float* out = (float*)d_out;

    // workspace: t (32MB) | xbf/attnbf alias (8MB) | wtT (4MB) | woT (2MB) = 46MB
    float*  t      = (float*)d_ws;
    ushort* xbf    = (ushort*)(t + (size_t)NPOS * TW);
    ushort* attnbf = xbf;                         // dead after GEMM1 -> reuse
    ushort* wtT    = xbf + (size_t)NPOS * DIMX;
    ushort* woT    = wtT + (size_t)TW * DIMX;

    // 0) precision conversions
    cast_bf16<<<(NPOS*DIMX/4 + 255)/256, 256, 0, stream>>>(x, xbf, NPOS*DIMX/4);
    transpose_cast<<<dim3(TW/32, DIMX/32),   256, 0, stream>>>(w_t, wtT, DIMX, TW);
    transpose_cast<<<dim3(DIMX/32, DIMX/32), 256, 0, stream>>>(w_o, woT, DIMX, DIMX);

    // 1) t = x @ w_t   (bf16 MFMA, fp32 out)
    gemm_bf16_mfma<<<dim3(TW/128, NPOS/128), 256, 0, stream>>>(xbf, wtT, t, NPOS, TW, DIMX);
    // 2) rotate q,k in place (masked, fp32)
    rotate_qk<<<NPOS, 256, 0, stream>>>(t, mask, rot);
    // 3) fused Taylor attention -> attn bf16 [NPOS, DIMX]
    taylor_attn<<<dim3(BATCH*NH, SEQ/64), 256, 0, stream>>>(t, mask, attnbf);
    // 4) out = attn @ w_o  (bf16 MFMA, fp32 out)
    gemm_bf16_mfma<<<dim3(DIMX/128, NPOS/128), 256, 0, stream>>>(attnbf, woT, out, NPOS, DIMX, DIMX);
}

// Round 3
// 153.530 us; speedup vs baseline: 3.6941x; 1.8460x over previous
//
#include <hip/hip_runtime.h>
#include <cstdint>
#include <cstddef>

#define DIMX  1024
#define NH    8
#define HD    64
#define QKD   512            // NH*HD
#define VDD   128            // DIMX/NH
#define BATCH 4
#define SEQ   1024
#define NPOS  (BATCH*SEQ)    // 4096
#define TW    (2*QKD + DIMX) // 2048
#define SCALE 0.125f         // HD^-0.5

typedef __bf16 bf16x8 __attribute__((ext_vector_type(8)));
typedef float  f32x4  __attribute__((ext_vector_type(4)));

__device__ __forceinline__ ushort f2bf(float f) {
    unsigned b = __float_as_uint(f);
    return (ushort)((b + 0x7FFFu + ((b >> 16) & 1u)) >> 16);   // RNE, finite data
}

#define GLD16(src, dst) __builtin_amdgcn_global_load_lds(                      \
    (const __attribute__((address_space(1))) unsigned int*)(src),              \
    (__attribute__((address_space(3))) unsigned int*)(dst), 16, 0, 0)

// swizzled LDS element index for [row][col] tiles with 64-elem (128B) rows
#define SW(row, col) ((row)*64 + ((col) ^ (((row)&7)<<3)))

// ---------------------------------------------------------------------------
// fp32 -> bf16 cast (same layout). n4 = elem_count/4.
// ---------------------------------------------------------------------------
__global__ __launch_bounds__(256)
void cast_bf16(const float* __restrict__ in, ushort* __restrict__ out, int n4)
{
    const int i = blockIdx.x * 256 + threadIdx.x;
    if (i >= n4) return;
    float4 v = *(const float4*)(in + (size_t)i * 4);
    ushort4 o;
    o.x = f2bf(v.x); o.y = f2bf(v.y); o.z = f2bf(v.z); o.w = f2bf(v.w);
    *(ushort4*)(out + (size_t)i * 4) = o;
}

// ---------------------------------------------------------------------------
// W[K][N] fp32 -> WT[N][K] bf16 (transpose + cast). 32x32 tiles.
// ---------------------------------------------------------------------------
__global__ __launch_bounds__(256)
void transpose_cast(const float* __restrict__ W, ushort* __restrict__ WT,
                    int K, int N)
{
    __shared__ float tile[32][33];
    const int bn = blockIdx.x * 32;
    const int bk = blockIdx.y * 32;
    const int tx = threadIdx.x & 31;
    const int ty = threadIdx.x >> 5;
    #pragma unroll
    for (int i = ty; i < 32; i += 8)
        tile[i][tx] = W[(size_t)(bk + i) * N + bn + tx];
    __syncthreads();
    #pragma unroll
    for (int i = ty; i < 32; i += 8)
        WT[(size_t)(bn + i) * K + bk + tx] = f2bf(tile[tx][i]);
}

// ---------------------------------------------------------------------------
// bf16 MFMA GEMM: C[M][N] fp32 = A[M][K] * BT[N][K]^T. (unchanged, verified)
// ---------------------------------------------------------------------------
__global__ __launch_bounds__(256, 2)
void gemm_bf16_mfma(const ushort* __restrict__ A, const ushort* __restrict__ BT,
                    float* __restrict__ C, int M, int N, int K)
{
    __shared__ __align__(16) ushort lA[128 * 32];
    __shared__ __align__(16) ushort lB[128 * 32];

    const int tid  = threadIdx.x;
    const int lane = tid & 63;
    const int wave = tid >> 6;
    const int wr   = wave >> 1;
    const int wc   = wave & 1;
    const int bm   = blockIdx.y * 128;
    const int bn   = blockIdx.x * 128;

    const int r0 = wave * 32 + (lane >> 2);
    const int kc = (lane & 3) * 8;
    const ushort* a0 = A  + (size_t)(bm + r0) * K + kc;
    const ushort* a1 = A  + (size_t)(bm + r0 + 16) * K + kc;
    const ushort* b0 = BT + (size_t)(bn + r0) * K + kc;
    const ushort* b1 = BT + (size_t)(bn + r0 + 16) * K + kc;
    ushort* lA0 = lA + wave * 1024;
    ushort* lA1 = lA0 + 512;
    ushort* lB0 = lB + wave * 1024;
    ushort* lB1 = lB0 + 512;

    const int fr = lane & 15;
    const int kh = (lane >> 4) * 8;
    const ushort* ra = lA + (wr * 64 + fr) * 32 + kh;
    const ushort* rb = lB + (wc * 64 + fr) * 32 + kh;

    f32x4 acc[4][4] = {};

    for (int k0 = 0; k0 < K; k0 += 32) {
        GLD16(a0 + k0, lA0);
        GLD16(a1 + k0, lA1);
        GLD16(b0 + k0, lB0);
        GLD16(b1 + k0, lB1);
        asm volatile("s_waitcnt vmcnt(0)" ::: "memory");
        __syncthreads();
        bf16x8 af[4], bfr[4];
        #pragma unroll
        for (int m = 0; m < 4; ++m) af[m]  = *(const bf16x8*)(ra + m * 512);
        #pragma unroll
        for (int n = 0; n < 4; ++n) bfr[n] = *(const bf16x8*)(rb + n * 512);
        #pragma unroll
        for (int m = 0; m < 4; ++m)
            #pragma unroll
            for (int n = 0; n < 4; ++n)
                acc[m][n] = __builtin_amdgcn_mfma_f32_16x16x32_bf16(
                    af[m], bfr[n], acc[m][n], 0, 0, 0);
        __syncthreads();
    }

    const int orow = (lane >> 4) * 4;
    #pragma unroll
    for (int m = 0; m < 4; ++m)
        #pragma unroll
        for (int n = 0; n < 4; ++n) {
            float* dst = C + (size_t)(bm + wr * 64 + m * 16 + orow) * N
                           + bn + wc * 64 + n * 16 + fr;
            #pragma unroll
            for (int q = 0; q < 4; ++q)
                dst[(size_t)q * N] = acc[m][n][q];
        }
}

// ---------------------------------------------------------------------------
// In-place masked rotation of q,k inside t = [NPOS, TW]. (fp32, unchanged)
// ---------------------------------------------------------------------------
__global__ __launch_bounds__(256)
void rotate_qk(float* __restrict__ t, const int* __restrict__ mask,
               const float* __restrict__ rot)
{
    const int p   = blockIdx.x;
    const int tid = threadIdx.x;
    if (mask[p] == 0) return;

    __shared__ float R[64][69];
    __shared__ float qv[QKD];
    __shared__ float kv[QKD];

    float* tq = t + (size_t)p * TW;

    {
        const float* Rg = rot + (size_t)p * 4096;
        const int base = tid * 16;
        const int r = base >> 6, c = base & 63;
        #pragma unroll
        for (int x = 0; x < 16; x += 4) {
            float4 v = *(const float4*)(Rg + base + x);
            R[r][c+x+0] = v.x; R[r][c+x+1] = v.y;
            R[r][c+x+2] = v.z; R[r][c+x+3] = v.w;
        }
        float2 q2 = *(const float2*)(tq + tid*2);
        float2 k2 = *(const float2*)(tq + QKD + tid*2);
        qv[tid*2]   = q2.x; qv[tid*2+1] = q2.y;
        kv[tid*2]   = k2.x; kv[tid*2+1] = k2.y;
    }
    __syncthreads();

    #pragma unroll
    for (int ph = 0; ph < 2; ++ph) {
        const int h = (tid >> 6) + ph*4;
        const int i = tid & 63;
        const float* qh = &qv[h*64];
        const float* kh2 = &kv[h*64];
        float aq = 0.f, ak = 0.f;
        #pragma unroll 8
        for (int j = 0; j < 64; ++j) {
            aq = fmaf(R[i][j], qh[j], aq);
            ak = fmaf(R[j][i], kh2[j], ak);
        }
        tq[h*64 + i]       = aq;
        tq[QKD + h*64 + i] = ak;
    }
}

// ---------------------------------------------------------------------------
// Pack rotated q,k from t into head-major bf16: Qb/Kb [B*H][S][64].
// One block per position; thread covers 4 elems of the 1024 q|k columns.
// ---------------------------------------------------------------------------
__global__ __launch_bounds__(256)
void pack_qk(const float* __restrict__ t, ushort* __restrict__ Qb,
             ushort* __restrict__ Kb)
{
    const int pos = blockIdx.x;
    const int tid = threadIdx.x;
    const int b = pos >> 10, s = pos & 1023;
    const int e = tid * 4;                      // 0..1020
    float4 v = *(const float4*)(t + (size_t)pos * TW + e);
    ushort o[4] = {f2bf(v.x), f2bf(v.y), f2bf(v.z), f2bf(v.w)};
    const int within = e & 511;
    const int h = within >> 6, d = within & 63;
    ushort* dst = (e < QKD) ? Qb : Kb;
    *(ushort4*)&dst[((size_t)(b*NH + h)*SEQ + s)*HD + d] = *(ushort4*)o;
}

// ---------------------------------------------------------------------------
// Pack V transposed per head: Vt[B*H][vd=128][S] bf16.
// Block = (bh, 64-position tile). item (vd, j): gather 8 strided fp32, store 16B.
// ---------------------------------------------------------------------------
__global__ __launch_bounds__(256)
void pack_v(const float* __restrict__ t, ushort* __restrict__ Vt)
{
    const int bh = blockIdx.x;
    const int st = blockIdx.y;
    const int b = bh >> 3, h = bh & 7;
    const int tid = threadIdx.x;
    #pragma unroll
    for (int r = 0; r < 4; ++r) {
        const int it = r * 256 + tid;
        const int vd = it & 127, j = it >> 7;   // j 0..7
        const float* src = t + (size_t)(b*SEQ + st*64 + j*8) * TW + 2*QKD + h*VDD + vd;
        ushort o[8];
        #pragma unroll
        for (int i = 0; i < 8; ++i) o[i] = f2bf(src[(size_t)i * TW]);
        *(uint4*)&Vt[((size_t)bh*VDD + vd)*SEQ + st*64 + j*8] = *(uint4*)o;
    }
}

// ---------------------------------------------------------------------------
// MFMA Taylor attention. Block = (b*8+h, 64 q-rows), 256 threads = 4 waves,
// wave owns 16 q-rows. K/V double-buffered swizzled LDS; P via swizzled LDS.
// ---------------------------------------------------------------------------
__global__ __launch_bounds__(256, 2)
void taylor_attn_mfma(const ushort* __restrict__ Qb, const ushort* __restrict__ Kb,
                      const ushort* __restrict__ Vt, const int* __restrict__ mask,
                      ushort* __restrict__ attn)
{
    const int bh  = blockIdx.x;
    const int qt  = blockIdx.y;
    const int b   = bh >> 3, h = bh & 7;
    const int tid = threadIdx.x;
    const int lane = tid & 63;
    const int wave = tid >> 6;
    const int l15 = lane & 15;
    const int l4  = lane >> 4;               // 0..3

    __shared__ __align__(16) ushort Ks[2][64*64];    // [key][d]  swizzled
    __shared__ __align__(16) ushort Vs[2][128*64];   // [vd][key] swizzled
    __shared__ __align__(16) ushort Ps[64*64];       // [q][key]  swizzled
    __shared__ float mks[2][64];

    // Q fragments in registers: rows = qt*64 + wave*16 + l15, d = ks*32+l4*8
    const ushort* qrow = Qb + ((size_t)bh*SEQ + qt*64 + wave*16 + l15) * HD;
    bf16x8 qf0 = *(const bf16x8*)(qrow + l4*8);
    bf16x8 qf1 = *(const bf16x8*)(qrow + 32 + l4*8);

    const ushort* Ktile = Kb + (size_t)bh * SEQ * HD;        // tiles of 4096 elems
    const ushort* Vbase = Vt + (size_t)bh * VDD * SEQ;       // rows stride SEQ
    const int*    mbase = mask + b * SEQ;

    uint4 kreg[2], vreg[4];
    float mreg = 0.f;

    f32x4 oacc[8] = {};
    float dsum[4] = {};

    // ---- prologue: stage tile 0 ----
    {
        #pragma unroll
        for (int r = 0; r < 2; ++r)
            kreg[r] = *(const uint4*)(Ktile + (size_t)(r*256 + tid) * 8);
        #pragma unroll
        for (int r = 0; r < 4; ++r) {
            const int c = r*256 + tid, vd = c >> 3, j = c & 7;
            vreg[r] = *(const uint4*)(Vbase + (size_t)vd*SEQ + j*8);
        }
        if (tid < 64) mreg = (mbase[tid] != 0) ? 1.f : 0.f;
        #pragma unroll
        for (int r = 0; r < 2; ++r) {
            const int c = r*256 + tid, row = c >> 3, col = (c & 7) * 8;
            *(uint4*)&Ks[0][SW(row, col)] = kreg[r];
        }
        #pragma unroll
        for (int r = 0; r < 4; ++r) {
            const int c = r*256 + tid, vd = c >> 3, col = (c & 7) * 8;
            *(uint4*)&Vs[0][SW(vd, col)] = vreg[r];
        }
        if (tid < 64) mks[0][tid] = mreg;
    }

    for (int kt = 0; kt < 16; ++kt) {
        const int cur = kt & 1;
        // issue next tile's global loads early (hide under MFMA)
        if (kt < 15) {
            #pragma unroll
            for (int r = 0; r < 2; ++r)
                kreg[r] = *(const uint4*)(Ktile + (size_t)(kt+1)*4096
                                          + (size_t)(r*256 + tid) * 8);
            #pragma unroll
            for (int r = 0; r < 4; ++r) {
                const int c = r*256 + tid, vd = c >> 3, j = c & 7;
                vreg[r] = *(const uint4*)(Vbase + (size_t)vd*SEQ + (kt+1)*64 + j*8);
            }
            if (tid < 64) mreg = (mbase[(kt+1)*64 + tid] != 0) ? 1.f : 0.f;
        }
        __syncthreads();                    // staged tile (and P region) ready

        // ---- QK^T: S[16q x 64k] per wave ----
        f32x4 sf[4] = {};
        #pragma unroll
        for (int nf = 0; nf < 4; ++nf) {
            const int row = nf*16 + l15;
            bf16x8 kf0 = *(const bf16x8*)&Ks[cur][SW(row, l4*8)];
            bf16x8 kf1 = *(const bf16x8*)&Ks[cur][SW(row, 32 + l4*8)];
            sf[nf] = __builtin_amdgcn_mfma_f32_16x16x32_bf16(qf0, kf0, sf[nf], 0, 0, 0);
            sf[nf] = __builtin_amdgcn_mfma_f32_16x16x32_bf16(qf1, kf1, sf[nf], 0, 0, 0);
        }

        // ---- scores -> P (bf16 LDS) + denominator ----
        #pragma unroll
        for (int nf = 0; nf < 4; ++nf) {
            const float mkv = mks[cur][nf*16 + l15];
            #pragma unroll
            for (int rg = 0; rg < 4; ++rg) {
                const float s  = sf[nf][rg] * SCALE;
                const float sc = (1.f + s + 0.5f*s*s) * mkv;
                dsum[rg] += sc;
                const int row = wave*16 + l4*4 + rg;
                Ps[SW(row, nf*16 + l15)] = f2bf(sc);
            }
        }
        __syncthreads();                    // P visible to all waves

        // ---- PV: out[16q x 128vd] += P @ V^T ----
        const int prow = wave*16 + l15;
        #pragma unroll
        for (int ks = 0; ks < 2; ++ks) {
            bf16x8 pa = *(const bf16x8*)&Ps[SW(prow, ks*32 + l4*8)];
            #pragma unroll
            for (int nf = 0; nf < 8; ++nf) {
                const int vrow = nf*16 + l15;
                bf16x8 vf = *(const bf16x8*)&Vs[cur][SW(vrow, ks*32 + l4*8)];
                oacc[nf] = __builtin_amdgcn_mfma_f32_16x16x32_bf16(pa, vf, oacc[nf], 0, 0, 0);
            }
        }

        // ---- commit next tile into the other buffer (no barrier needed) ----
        if (kt < 15) {
            const int nb = cur ^ 1;
            #pragma unroll
            for (int r = 0; r < 2; ++r) {
                const int c = r*256 + tid, row = c >> 3, col = (c & 7) * 8;
                *(uint4*)&Ks[nb][SW(row, col)] = kreg[r];
            }
            #pragma unroll
            for (int r = 0; r < 4; ++r) {
                const int c = r*256 + tid, vd = c >> 3, col = (c & 7) * 8;
                *(uint4*)&Vs[nb][SW(vd, col)] = vreg[r];
            }
            if (tid < 64) mks[nb][tid] = mreg;
        }
    }

    // ---- denominator reduce across the 16 key-lanes, normalize, store ----
    #pragma unroll
    for (int rg = 0; rg < 4; ++rg) {
        float d = dsum[rg];
        d += __shfl_xor(d, 1);
        d += __shfl_xor(d, 2);
        d += __shfl_xor(d, 4);
        d += __shfl_xor(d, 8);
        dsum[rg] = 1.f / fmaxf(d, 1e-6f);
    }
    ushort* orow = attn + ((size_t)(b*SEQ + qt*64 + wave*16 + l4*4)) * DIMX
                 + h*VDD + l15;
    #pragma unroll
    for (int nf = 0; nf < 8; ++nf)
        #pragma unroll
        for (int rg = 0; rg < 4; ++rg)
            orow[(size_t)rg*DIMX + nf*16] = f2bf(oacc[nf][rg] * dsum[rg]);
}

// ---------------------------------------------------------------------------
extern "C" void kernel_launch(void* const* d_in, const int* in_sizes, int n_in,
                              void* d_out, int out_size, void* d_ws, size_t ws_size,
                              hipStream_t stream)
{
    const float* x    = (const float*)d_in[0];
    const int*   mask = (const int*)d_in[1];
    const float* rot  = (const float*)d_in[2];
    const float* w_t  = (const float*)d_in[3];
    const float* w_o  = (const float*)d_in[4];
    float* out = (float*)d_out;

    // workspace layout (62 MB):
    // t 32MB | xbf/attnbf 8MB | wtT 4MB | woT 2MB | Qb 4MB | Kb 4MB | Vt 8MB
    float*  t      = (float*)d_ws;
    ushort* xbf    = (ushort*)(t + (size_t)NPOS * TW);
    ushort* attnbf = xbf;                            // dead after GEMM1 -> reuse
    ushort* wtT    = xbf + (size_t)NPOS * DIMX;
    ushort* woT    = wtT + (size_t)TW * DIMX;
    ushort* Qb     = woT + (size_t)DIMX * DIMX;
    ushort* Kb     = Qb  + (size_t)BATCH * NH * SEQ * HD;
    ushort* Vtp    = Kb  + (size_t)BATCH * NH * SEQ * HD;

    // 0) precision conversions
    cast_bf16<<<(NPOS*DIMX/4 + 255)/256, 256, 0, stream>>>(x, xbf, NPOS*DIMX/4);
    transpose_cast<<<dim3(TW/32, DIMX/32),   256, 0, stream>>>(w_t, wtT, DIMX, TW);
    transpose_cast<<<dim3(DIMX/32, DIMX/32), 256, 0, stream>>>(w_o, woT, DIMX, DIMX);

    // 1) t = x @ w_t
    gemm_bf16_mfma<<<dim3(TW/128, NPOS/128), 256, 0, stream>>>(xbf, wtT, t, NPOS, TW, DIMX);
    // 2) rotate q,k in place (masked, fp32)
    rotate_qk<<<NPOS, 256, 0, stream>>>(t, mask, rot);
    // 3) pack bf16 operands for attention
    pack_qk<<<NPOS, 256, 0, stream>>>(t, Qb, Kb);
    pack_v<<<dim3(BATCH*NH, SEQ/64), 256, 0, stream>>>(t, Vtp);
    // 4) fused MFMA Taylor attention -> attnbf [NPOS, DIMX] bf16
    taylor_attn_mfma<<<dim3(BATCH*NH, SEQ/64), 256, 0, stream>>>(Qb, Kb, Vtp, mask, attnbf);
    // 5) out = attn @ w_o
    gemm_bf16_mfma<<<dim3(DIMX/128, NPOS/128), 256, 0, stream>>>(attnbf, woT, out, NPOS, DIMX, DIMX);
}

// Round 4
// 116.367 us; speedup vs baseline: 4.8739x; 1.3194x over previous
//
#include <hip/hip_runtime.h>
#include <cstdint>
#include <cstddef>

#define DIMX  1024
#define NH    8
#define HD    64
#define QKD   512            // NH*HD
#define VDD   128            // DIMX/NH
#define BATCH 4
#define SEQ   1024
#define NPOS  (BATCH*SEQ)    // 4096
#define TW    (2*QKD + DIMX) // 2048
#define SCALE 0.125f         // HD^-0.5

typedef __bf16 bf16x8 __attribute__((ext_vector_type(8)));
typedef float  f32x4  __attribute__((ext_vector_type(4)));

__device__ __forceinline__ ushort f2bf(float f) {
    unsigned b = __float_as_uint(f);
    return (ushort)((b + 0x7FFFu + ((b >> 16) & 1u)) >> 16);   // RNE, finite data
}

#define GLD16(src, dst) __builtin_amdgcn_global_load_lds(                      \
    (const __attribute__((address_space(1))) unsigned int*)(src),              \
    (__attribute__((address_space(3))) unsigned int*)(dst), 16, 0, 0)

// swizzled LDS element index for [row][col] tiles with 64-elem (128B) rows
#define SW(row, col) ((row)*64 + ((col) ^ (((row)&7)<<3)))

// XCD-aware block swizzle (bijective: nwg % 8 == 0 for all our grids)
__device__ __forceinline__ int2 xcd_swz(int gx, int gy) {
    const int nwg = gx * gy;
    int id = blockIdx.y * gx + blockIdx.x;
    id = (id & 7) * (nwg >> 3) + (id >> 3);
    return make_int2(id % gx, id / gx);
}

// ---------------------------------------------------------------------------
// fp32 -> bf16 cast (same layout). n4 = elem_count/4.
// ---------------------------------------------------------------------------
__global__ __launch_bounds__(256)
void cast_bf16(const float* __restrict__ in, ushort* __restrict__ out, int n4)
{
    const int i = blockIdx.x * 256 + threadIdx.x;
    if (i >= n4) return;
    float4 v = *(const float4*)(in + (size_t)i * 4);
    ushort4 o;
    o.x = f2bf(v.x); o.y = f2bf(v.y); o.z = f2bf(v.z); o.w = f2bf(v.w);
    *(ushort4*)(out + (size_t)i * 4) = o;
}

// ---------------------------------------------------------------------------
// W[K][N] fp32 -> WT[N][K] bf16 (transpose + cast). 32x32 tiles.
// ---------------------------------------------------------------------------
__global__ __launch_bounds__(256)
void transpose_cast(const float* __restrict__ W, ushort* __restrict__ WT,
                    int K, int N)
{
    __shared__ float tile[32][33];
    const int bn = blockIdx.x * 32;
    const int bk = blockIdx.y * 32;
    const int tx = threadIdx.x & 31;
    const int ty = threadIdx.x >> 5;
    #pragma unroll
    for (int i = ty; i < 32; i += 8)
        tile[i][tx] = W[(size_t)(bk + i) * N + bn + tx];
    __syncthreads();
    #pragma unroll
    for (int i = ty; i < 32; i += 8)
        WT[(size_t)(bn + i) * K + bk + tx] = f2bf(tile[tx][i]);
}

// ---------------------------------------------------------------------------
// GEMM1 with split epilogue: computes X[M,1024] @ WtT^T -> cols [0,1024)
// go to t1 fp32 (q,k), cols [1024,2048) go transposed-bf16 into Vt[bh][vd][S].
// 128x128 tile, BK=32, 4 waves, m97 structure.
// ---------------------------------------------------------------------------
__global__ __launch_bounds__(256, 2)
void gemm_qkv(const ushort* __restrict__ A, const ushort* __restrict__ BT,
              float* __restrict__ t1, ushort* __restrict__ Vt)
{
    const int K = DIMX, N = TW;
    __shared__ __align__(16) ushort lA[128 * 32];
    __shared__ __align__(16) ushort lB[128 * 32];

    const int2 bij = xcd_swz(N/128, NPOS/128);
    const int tid  = threadIdx.x;
    const int lane = tid & 63;
    const int wave = tid >> 6;
    const int wr   = wave >> 1;
    const int wc   = wave & 1;
    const int bm   = bij.y * 128;
    const int bn   = bij.x * 128;

    const int r0 = wave * 32 + (lane >> 2);
    const int kc = (lane & 3) * 8;
    const ushort* a0 = A  + (size_t)(bm + r0) * K + kc;
    const ushort* a1 = A  + (size_t)(bm + r0 + 16) * K + kc;
    const ushort* b0 = BT + (size_t)(bn + r0) * K + kc;
    const ushort* b1 = BT + (size_t)(bn + r0 + 16) * K + kc;
    ushort* lA0 = lA + wave * 1024;
    ushort* lA1 = lA0 + 512;
    ushort* lB0 = lB + wave * 1024;
    ushort* lB1 = lB0 + 512;

    const int fr = lane & 15;
    const int kh = (lane >> 4) * 8;
    const ushort* ra = lA + (wr * 64 + fr) * 32 + kh;
    const ushort* rb = lB + (wc * 64 + fr) * 32 + kh;

    f32x4 acc[4][4] = {};

    for (int k0 = 0; k0 < K; k0 += 32) {
        GLD16(a0 + k0, lA0);
        GLD16(a1 + k0, lA1);
        GLD16(b0 + k0, lB0);
        GLD16(b1 + k0, lB1);
        asm volatile("s_waitcnt vmcnt(0)" ::: "memory");
        __syncthreads();
        bf16x8 af[4], bfr[4];
        #pragma unroll
        for (int m = 0; m < 4; ++m) af[m]  = *(const bf16x8*)(ra + m * 512);
        #pragma unroll
        for (int n = 0; n < 4; ++n) bfr[n] = *(const bf16x8*)(rb + n * 512);
        #pragma unroll
        for (int m = 0; m < 4; ++m)
            #pragma unroll
            for (int n = 0; n < 4; ++n)
                acc[m][n] = __builtin_amdgcn_mfma_f32_16x16x32_bf16(
                    af[m], bfr[n], acc[m][n], 0, 0, 0);
        __syncthreads();
    }

    const int orow = (lane >> 4) * 4;
    if (bn < 1024) {
        // q,k region -> fp32 t1 [NPOS][1024]
        #pragma unroll
        for (int m = 0; m < 4; ++m)
            #pragma unroll
            for (int n = 0; n < 4; ++n) {
                float* dst = t1 + (size_t)(bm + wr * 64 + m * 16 + orow) * 1024
                               + bn + wc * 64 + n * 16 + fr;
                #pragma unroll
                for (int q = 0; q < 4; ++q)
                    dst[(size_t)q * 1024] = acc[m][n][q];
            }
    } else {
        // v region -> bf16 Vt[bh][vd][S]; 4 output rows are contiguous in S
        #pragma unroll
        for (int m = 0; m < 4; ++m)
            #pragma unroll
            for (int n = 0; n < 4; ++n) {
                const int row0 = bm + wr * 64 + m * 16 + orow;   // 4-aligned
                const int cv   = bn + wc * 64 + n * 16 + fr - 1024;
                const int hh = cv >> 7, vd = cv & 127;
                const int bb = row0 >> 10, ss = row0 & 1023;
                ushort o4[4];
                #pragma unroll
                for (int q = 0; q < 4; ++q) o4[q] = f2bf(acc[m][n][q]);
                *(ushort4*)&Vt[((size_t)(bb*NH + hh)*VDD + vd)*SEQ + ss] =
                    *(ushort4*)o4;
            }
    }
}

// ---------------------------------------------------------------------------
// GEMM2: C[M][N] fp32 = A[M][K] * BT[N][K]^T (both bf16). + XCD swizzle.
// ---------------------------------------------------------------------------
__global__ __launch_bounds__(256, 2)
void gemm_bf16_mfma(const ushort* __restrict__ A, const ushort* __restrict__ BT,
                    float* __restrict__ C, int M, int N, int K)
{
    __shared__ __align__(16) ushort lA[128 * 32];
    __shared__ __align__(16) ushort lB[128 * 32];

    const int2 bij = xcd_swz(N/128, M/128);
    const int tid  = threadIdx.x;
    const int lane = tid & 63;
    const int wave = tid >> 6;
    const int wr   = wave >> 1;
    const int wc   = wave & 1;
    const int bm   = bij.y * 128;
    const int bn   = bij.x * 128;

    const int r0 = wave * 32 + (lane >> 2);
    const int kc = (lane & 3) * 8;
    const ushort* a0 = A  + (size_t)(bm + r0) * K + kc;
    const ushort* a1 = A  + (size_t)(bm + r0 + 16) * K + kc;
    const ushort* b0 = BT + (size_t)(bn + r0) * K + kc;
    const ushort* b1 = BT + (size_t)(bn + r0 + 16) * K + kc;
    ushort* lA0 = lA + wave * 1024;
    ushort* lA1 = lA0 + 512;
    ushort* lB0 = lB + wave * 1024;
    ushort* lB1 = lB0 + 512;

    const int fr = lane & 15;
    const int kh = (lane >> 4) * 8;
    const ushort* ra = lA + (wr * 64 + fr) * 32 + kh;
    const ushort* rb = lB + (wc * 64 + fr) * 32 + kh;

    f32x4 acc[4][4] = {};

    for (int k0 = 0; k0 < K; k0 += 32) {
        GLD16(a0 + k0, lA0);
        GLD16(a1 + k0, lA1);
        GLD16(b0 + k0, lB0);
        GLD16(b1 + k0, lB1);
        asm volatile("s_waitcnt vmcnt(0)" ::: "memory");
        __syncthreads();
        bf16x8 af[4], bfr[4];
        #pragma unroll
        for (int m = 0; m < 4; ++m) af[m]  = *(const bf16x8*)(ra + m * 512);
        #pragma unroll
        for (int n = 0; n < 4; ++n) bfr[n] = *(const bf16x8*)(rb + n * 512);
        #pragma unroll
        for (int m = 0; m < 4; ++m)
            #pragma unroll
            for (int n = 0; n < 4; ++n)
                acc[m][n] = __builtin_amdgcn_mfma_f32_16x16x32_bf16(
                    af[m], bfr[n], acc[m][n], 0, 0, 0);
        __syncthreads();
    }

    const int orow = (lane >> 4) * 4;
    #pragma unroll
    for (int m = 0; m < 4; ++m)
        #pragma unroll
        for (int n = 0; n < 4; ++n) {
            float* dst = C + (size_t)(bm + wr * 64 + m * 16 + orow) * N
                           + bn + wc * 64 + n * 16 + fr;
            #pragma unroll
            for (int q = 0; q < 4; ++q)
                dst[(size_t)q * N] = acc[m][n][q];
        }
}

// ---------------------------------------------------------------------------
// Fused masked rotation + bf16 pack: t1[:,0:1024] (q|k fp32) -> Qb/Kb
// head-major bf16 [B*H][S][64]. One block per position.
// ---------------------------------------------------------------------------
__global__ __launch_bounds__(256)
void rotate_pack_qk(const float* __restrict__ t1, const int* __restrict__ mask,
                    const float* __restrict__ rot, ushort* __restrict__ Qb,
                    ushort* __restrict__ Kb)
{
    const int p   = blockIdx.x;
    const int tid = threadIdx.x;
    const int b = p >> 10, s = p & 1023;
    const bool rotated = (mask[p] != 0);   // block-uniform

    __shared__ float R[64][69];
    __shared__ float qv[QKD];
    __shared__ float kv[QKD];

    const float* tq = t1 + (size_t)p * 1024;
    {
        float2 q2 = *(const float2*)(tq + tid*2);
        float2 k2 = *(const float2*)(tq + QKD + tid*2);
        qv[tid*2]   = q2.x; qv[tid*2+1] = q2.y;
        kv[tid*2]   = k2.x; kv[tid*2+1] = k2.y;
        if (rotated) {
            const float* Rg = rot + (size_t)p * 4096;
            const int base = tid * 16;
            const int r = base >> 6, c = base & 63;
            #pragma unroll
            for (int x = 0; x < 16; x += 4) {
                float4 v = *(const float4*)(Rg + base + x);
                R[r][c+x+0] = v.x; R[r][c+x+1] = v.y;
                R[r][c+x+2] = v.z; R[r][c+x+3] = v.w;
            }
        }
    }
    __syncthreads();

    #pragma unroll
    for (int ph = 0; ph < 2; ++ph) {
        const int h = (tid >> 6) + ph*4;
        const int i = tid & 63;
        const float* qh  = &qv[h*64];
        const float* kh2 = &kv[h*64];
        float aq, ak;
        if (rotated) {
            aq = 0.f; ak = 0.f;
            #pragma unroll 8
            for (int j = 0; j < 64; ++j) {
                aq = fmaf(R[i][j], qh[j], aq);    // (R q)_i
                ak = fmaf(R[j][i], kh2[j], ak);   // (R^T k)_i
            }
        } else {
            aq = qh[i]; ak = kh2[i];
        }
        const size_t dst = ((size_t)(b*NH + h)*SEQ + s)*HD + i;
        Qb[dst] = f2bf(aq);
        Kb[dst] = f2bf(ak);
    }
}

// ---------------------------------------------------------------------------
// MFMA Taylor attention, 2-phase GLD16 staging, 1 barrier/iter.
// Block = (b*8+h, 64 q-rows), 4 waves x 16 q-rows. P is wave-private LDS.
// ---------------------------------------------------------------------------
__global__ __launch_bounds__(256, 2)
void taylor_attn_mfma(const ushort* __restrict__ Qb, const ushort* __restrict__ Kb,
                      const ushort* __restrict__ Vt, const int* __restrict__ mask,
                      ushort* __restrict__ attn)
{
    const int bh  = blockIdx.x;
    const int qt  = blockIdx.y;
    const int b   = bh >> 3, h = bh & 7;
    const int tid = threadIdx.x;
    const int lane = tid & 63;
    const int wave = tid >> 6;
    const int l15 = lane & 15;
    const int l4  = lane >> 4;

    __shared__ __align__(16) ushort Ks[2][64*64];    // swizzled via source perm
    __shared__ __align__(16) ushort Vs[2][128*64];
    __shared__ __align__(16) ushort Ps[64*64];       // [q][key], wave-private rows
    __shared__ float mskAll[SEQ];                    // whole-seq mask, staged once

    // stage mask once (avoids mid-loop vmcnt pollution)
    {
        int4 mv = *(const int4*)(mask + b*SEQ + tid*4);
        float4 f = make_float4(mv.x ? 1.f : 0.f, mv.y ? 1.f : 0.f,
                               mv.z ? 1.f : 0.f, mv.w ? 1.f : 0.f);
        *(float4*)&mskAll[tid*4] = f;
    }

    // Q fragments in registers
    const ushort* qrow = Qb + ((size_t)bh*SEQ + qt*64 + wave*16 + l15) * HD;
    bf16x8 qf0 = *(const bf16x8*)(qrow + l4*8);
    bf16x8 qf1 = *(const bf16x8*)(qrow + 32 + l4*8);

    // GLD16 per-lane pre-swizzled source pointers (dest linear, read swizzled)
    const int sub  = lane >> 3;                 // row-within-8 == row&7
    const int scol = ((lane & 7) * 8) ^ (sub << 3);
    const ushort* kp0 = Kb + (size_t)bh*SEQ*HD + (size_t)(8*(wave*2+0) + sub)*HD + scol;
    const ushort* kp1 = Kb + (size_t)bh*SEQ*HD + (size_t)(8*(wave*2+1) + sub)*HD + scol;
    const ushort* vp0 = Vt + (size_t)bh*VDD*SEQ + (size_t)(8*(wave*4+0) + sub)*SEQ + scol;
    const ushort* vp1 = Vt + (size_t)bh*VDD*SEQ + (size_t)(8*(wave*4+1) + sub)*SEQ + scol;
    const ushort* vp2 = Vt + (size_t)bh*VDD*SEQ + (size_t)(8*(wave*4+2) + sub)*SEQ + scol;
    const ushort* vp3 = Vt + (size_t)bh*VDD*SEQ + (size_t)(8*(wave*4+3) + sub)*SEQ + scol;

#define ISSUE_TILE(buf, ktn) do {                                          \
    GLD16(kp0 + (size_t)(ktn)*4096, &Ks[buf][(wave*2+0)*512]);             \
    GLD16(kp1 + (size_t)(ktn)*4096, &Ks[buf][(wave*2+1)*512]);             \
    GLD16(vp0 + (size_t)(ktn)*64,   &Vs[buf][(wave*4+0)*512]);             \
    GLD16(vp1 + (size_t)(ktn)*64,   &Vs[buf][(wave*4+1)*512]);             \
    GLD16(vp2 + (size_t)(ktn)*64,   &Vs[buf][(wave*4+2)*512]);             \
    GLD16(vp3 + (size_t)(ktn)*64,   &Vs[buf][(wave*4+3)*512]);             \
} while (0)

    f32x4 oacc[8] = {};
    float dsum[4] = {};

    ISSUE_TILE(0, 0);

    for (int kt = 0; kt < 16; ++kt) {
        const int cur = kt & 1;
        asm volatile("s_waitcnt vmcnt(0)" ::: "memory");   // prev-issued tile landed
        __syncthreads();                                   // all waves' parts visible
        if (kt < 15) ISSUE_TILE(cur ^ 1, kt + 1);          // overlap with compute

        // ---- QK^T: S[16q x 64k] per wave ----
        f32x4 sf[4] = {};
        #pragma unroll
        for (int nf = 0; nf < 4; ++nf) {
            const int row = nf*16 + l15;
            bf16x8 kf0 = *(const bf16x8*)&Ks[cur][SW(row, l4*8)];
            bf16x8 kf1 = *(const bf16x8*)&Ks[cur][SW(row, 32 + l4*8)];
            sf[nf] = __builtin_amdgcn_mfma_f32_16x16x32_bf16(qf0, kf0, sf[nf], 0, 0, 0);
            sf[nf] = __builtin_amdgcn_mfma_f32_16x16x32_bf16(qf1, kf1, sf[nf], 0, 0, 0);
        }

        // ---- scores -> P (wave-private LDS rows; no barrier needed) ----
        const float* mrow = mskAll + kt*64;
        #pragma unroll
        for (int nf = 0; nf < 4; ++nf) {
            const float mkv = mrow[nf*16 + l15];
            #pragma unroll
            for (int rg = 0; rg < 4; ++rg) {
                const float s  = sf[nf][rg] * SCALE;
                const float sc = (1.f + s + 0.5f*s*s) * mkv;
                dsum[rg] += sc;
                Ps[SW(wave*16 + l4*4 + rg, nf*16 + l15)] = f2bf(sc);
            }
        }

        // ---- PV: out[16q x 128vd] += P @ V^T ----
        const int prow = wave*16 + l15;
        #pragma unroll
        for (int ks = 0; ks < 2; ++ks) {
            bf16x8 pa = *(const bf16x8*)&Ps[SW(prow, ks*32 + l4*8)];
            #pragma unroll
            for (int nf = 0; nf < 8; ++nf) {
                bf16x8 vf = *(const bf16x8*)&Vs[cur][SW(nf*16 + l15, ks*32 + l4*8)];
                oacc[nf] = __builtin_amdgcn_mfma_f32_16x16x32_bf16(pa, vf, oacc[nf], 0, 0, 0);
            }
        }
    }
#undef ISSUE_TILE

    // ---- denominator reduce across 16 key-lanes, normalize, store ----
    #pragma unroll
    for (int rg = 0; rg < 4; ++rg) {
        float d = dsum[rg];
        d += __shfl_xor(d, 1);
        d += __shfl_xor(d, 2);
        d += __shfl_xor(d, 4);
        d += __shfl_xor(d, 8);
        dsum[rg] = 1.f / fmaxf(d, 1e-6f);
    }
    ushort* orow = attn + ((size_t)(b*SEQ + qt*64 + wave*16 + l4*4)) * DIMX
                 + h*VDD + l15;
    #pragma unroll
    for (int nf = 0; nf < 8; ++nf)
        #pragma unroll
        for (int rg = 0; rg < 4; ++rg)
            orow[(size_t)rg*DIMX + nf*16] = f2bf(oacc[nf][rg] * dsum[rg]);
}

// ---------------------------------------------------------------------------
extern "C" void kernel_launch(void* const* d_in, const int* in_sizes, int n_in,
                              void* d_out, int out_size, void* d_ws, size_t ws_size,
                              hipStream_t stream)
{
    const float* x    = (const float*)d_in[0];
    const int*   mask = (const int*)d_in[1];
    const float* rot  = (const float*)d_in[2];
    const float* w_t  = (const float*)d_in[3];
    const float* w_o  = (const float*)d_in[4];
    float* out = (float*)d_out;

    // workspace (46 MB):
    // t1 16MB | xbf/attnbf 8MB | wtT 4MB | woT 2MB | Qb 4MB | Kb 4MB | Vt 8MB
    float*  t1     = (float*)d_ws;
    ushort* xbf    = (ushort*)(t1 + (size_t)NPOS * 1024);
    ushort* attnbf = xbf;                            // xbf dead after gemm_qkv
    ushort* wtT    = xbf + (size_t)NPOS * DIMX;
    ushort* woT    = wtT + (size_t)TW * DIMX;
    ushort* Qb     = woT + (size_t)DIMX * DIMX;
    ushort* Kb     = Qb  + (size_t)BATCH * NH * SEQ * HD;
    ushort* Vtp    = Kb  + (size_t)BATCH * NH * SEQ * HD;

    // 0) precision conversions
    cast_bf16<<<(NPOS*DIMX/4 + 255)/256, 256, 0, stream>>>(x, xbf, NPOS*DIMX/4);
    transpose_cast<<<dim3(TW/32, DIMX/32),   256, 0, stream>>>(w_t, wtT, DIMX, TW);
    transpose_cast<<<dim3(DIMX/32, DIMX/32), 256, 0, stream>>>(w_o, woT, DIMX, DIMX);

    // 1) qkv projection: q,k -> t1 fp32; v -> Vt bf16 (transposed per head)
    gemm_qkv<<<dim3(TW/128, NPOS/128), 256, 0, stream>>>(xbf, wtT, t1, Vtp);
    // 2) fused masked rotation + bf16 pack -> Qb, Kb
    rotate_pack_qk<<<NPOS, 256, 0, stream>>>(t1, mask, rot, Qb, Kb);
    // 3) fused MFMA Taylor attention -> attnbf [NPOS, DIMX] bf16
    taylor_attn_mfma<<<dim3(BATCH*NH, SEQ/64), 256, 0, stream>>>(Qb, Kb, Vtp, mask, attnbf);
    // 4) out = attn @ w_o
    gemm_bf16_mfma<<<dim3(DIMX/128, NPOS/128), 256, 0, stream>>>(attnbf, woT, out, NPOS, DIMX, DIMX);
}

// Round 5
// 114.331 us; speedup vs baseline: 4.9607x; 1.0178x over previous
//
#include <hip/hip_runtime.h>
#include <cstdint>
#include <cstddef>

#define DIMX  1024
#define NH    8
#define HD    64
#define QKD   512            // NH*HD
#define VDD   128            // DIMX/NH
#define BATCH 4
#define SEQ   1024
#define NPOS  (BATCH*SEQ)    // 4096
#define TW    (2*QKD + DIMX) // 2048
#define SCALE 0.125f         // HD^-0.5 (folded into Qb at pack time)

typedef __bf16 bf16x8 __attribute__((ext_vector_type(8)));
typedef float  f32x4  __attribute__((ext_vector_type(4)));

__device__ __forceinline__ ushort f2bf(float f) {
    unsigned b = __float_as_uint(f);
    return (ushort)((b + 0x7FFFu + ((b >> 16) & 1u)) >> 16);   // RNE, finite data
}

#define GLD16(src, dst) __builtin_amdgcn_global_load_lds(                      \
    (const __attribute__((address_space(1))) unsigned int*)(src),              \
    (__attribute__((address_space(3))) unsigned int*)(dst), 16, 0, 0)

// swizzled LDS element index for [row][col] tiles with 64-elem (128B) rows
#define SW(row, col) ((row)*64 + ((col) ^ (((row)&7)<<3)))

// XCD-aware block swizzle (bijective: nwg % 8 == 0 for all our grids)
__device__ __forceinline__ int2 xcd_swz(int gx, int gy) {
    const int nwg = gx * gy;
    int id = blockIdx.y * gx + blockIdx.x;
    id = (id & 7) * (nwg >> 3) + (id >> 3);
    return make_int2(id % gx, id / gx);
}

// ---------------------------------------------------------------------------
// fp32 -> bf16 cast (same layout). n4 = elem_count/4.
// ---------------------------------------------------------------------------
__global__ __launch_bounds__(256)
void cast_bf16(const float* __restrict__ in, ushort* __restrict__ out, int n4)
{
    const int i = blockIdx.x * 256 + threadIdx.x;
    if (i >= n4) return;
    float4 v = *(const float4*)(in + (size_t)i * 4);
    ushort4 o;
    o.x = f2bf(v.x); o.y = f2bf(v.y); o.z = f2bf(v.z); o.w = f2bf(v.w);
    *(ushort4*)(out + (size_t)i * 4) = o;
}

// ---------------------------------------------------------------------------
// W[K][N] fp32 -> WT[N][K] bf16 (transpose + cast). 32x32 tiles.
// ---------------------------------------------------------------------------
__global__ __launch_bounds__(256)
void transpose_cast(const float* __restrict__ W, ushort* __restrict__ WT,
                    int K, int N)
{
    __shared__ float tile[32][33];
    const int bn = blockIdx.x * 32;
    const int bk = blockIdx.y * 32;
    const int tx = threadIdx.x & 31;
    const int ty = threadIdx.x >> 5;
    #pragma unroll
    for (int i = ty; i < 32; i += 8)
        tile[i][tx] = W[(size_t)(bk + i) * N + bn + tx];
    __syncthreads();
    #pragma unroll
    for (int i = ty; i < 32; i += 8)
        WT[(size_t)(bn + i) * K + bk + tx] = f2bf(tile[tx][i]);
}

// ---------------------------------------------------------------------------
// GEMM1 with split epilogue: cols [0,1024) -> t1 fp32 (q,k);
// cols [1024,2048) -> transposed bf16 Vt[bh][vd][S].
// ---------------------------------------------------------------------------
__global__ __launch_bounds__(256, 2)
void gemm_qkv(const ushort* __restrict__ A, const ushort* __restrict__ BT,
              float* __restrict__ t1, ushort* __restrict__ Vt)
{
    const int K = DIMX, N = TW;
    __shared__ __align__(16) ushort lA[128 * 32];
    __shared__ __align__(16) ushort lB[128 * 32];

    const int2 bij = xcd_swz(N/128, NPOS/128);
    const int tid  = threadIdx.x;
    const int lane = tid & 63;
    const int wave = tid >> 6;
    const int wr   = wave >> 1;
    const int wc   = wave & 1;
    const int bm   = bij.y * 128;
    const int bn   = bij.x * 128;

    const int r0 = wave * 32 + (lane >> 2);
    const int kc = (lane & 3) * 8;
    const ushort* a0 = A  + (size_t)(bm + r0) * K + kc;
    const ushort* a1 = A  + (size_t)(bm + r0 + 16) * K + kc;
    const ushort* b0 = BT + (size_t)(bn + r0) * K + kc;
    const ushort* b1 = BT + (size_t)(bn + r0 + 16) * K + kc;
    ushort* lA0 = lA + wave * 1024;
    ushort* lA1 = lA0 + 512;
    ushort* lB0 = lB + wave * 1024;
    ushort* lB1 = lB0 + 512;

    const int fr = lane & 15;
    const int kh = (lane >> 4) * 8;
    const ushort* ra = lA + (wr * 64 + fr) * 32 + kh;
    const ushort* rb = lB + (wc * 64 + fr) * 32 + kh;

    f32x4 acc[4][4] = {};

    for (int k0 = 0; k0 < K; k0 += 32) {
        GLD16(a0 + k0, lA0);
        GLD16(a1 + k0, lA1);
        GLD16(b0 + k0, lB0);
        GLD16(b1 + k0, lB1);
        asm volatile("s_waitcnt vmcnt(0)" ::: "memory");
        __syncthreads();
        bf16x8 af[4], bfr[4];
        #pragma unroll
        for (int m = 0; m < 4; ++m) af[m]  = *(const bf16x8*)(ra + m * 512);
        #pragma unroll
        for (int n = 0; n < 4; ++n) bfr[n] = *(const bf16x8*)(rb + n * 512);
        #pragma unroll
        for (int m = 0; m < 4; ++m)
            #pragma unroll
            for (int n = 0; n < 4; ++n)
                acc[m][n] = __builtin_amdgcn_mfma_f32_16x16x32_bf16(
                    af[m], bfr[n], acc[m][n], 0, 0, 0);
        __syncthreads();
    }

    const int orow = (lane >> 4) * 4;
    if (bn < 1024) {
        #pragma unroll
        for (int m = 0; m < 4; ++m)
            #pragma unroll
            for (int n = 0; n < 4; ++n) {
                float* dst = t1 + (size_t)(bm + wr * 64 + m * 16 + orow) * 1024
                               + bn + wc * 64 + n * 16 + fr;
                #pragma unroll
                for (int q = 0; q < 4; ++q)
                    dst[(size_t)q * 1024] = acc[m][n][q];
            }
    } else {
        #pragma unroll
        for (int m = 0; m < 4; ++m)
            #pragma unroll
            for (int n = 0; n < 4; ++n) {
                const int row0 = bm + wr * 64 + m * 16 + orow;   // 4-aligned
                const int cv   = bn + wc * 64 + n * 16 + fr - 1024;
                const int hh = cv >> 7, vd = cv & 127;
                const int bb = row0 >> 10, ss = row0 & 1023;
                ushort o4[4];
                #pragma unroll
                for (int q = 0; q < 4; ++q) o4[q] = f2bf(acc[m][n][q]);
                *(ushort4*)&Vt[((size_t)(bb*NH + hh)*VDD + vd)*SEQ + ss] =
                    *(ushort4*)o4;
            }
    }
}

// ---------------------------------------------------------------------------
// GEMM2: C[M][N] fp32 = A[M][K] * BT[N][K]^T (both bf16). + XCD swizzle.
// ---------------------------------------------------------------------------
__global__ __launch_bounds__(256, 2)
void gemm_bf16_mfma(const ushort* __restrict__ A, const ushort* __restrict__ BT,
                    float* __restrict__ C, int M, int N, int K)
{
    __shared__ __align__(16) ushort lA[128 * 32];
    __shared__ __align__(16) ushort lB[128 * 32];

    const int2 bij = xcd_swz(N/128, M/128);
    const int tid  = threadIdx.x;
    const int lane = tid & 63;
    const int wave = tid >> 6;
    const int wr   = wave >> 1;
    const int wc   = wave & 1;
    const int bm   = bij.y * 128;
    const int bn   = bij.x * 128;

    const int r0 = wave * 32 + (lane >> 2);
    const int kc = (lane & 3) * 8;
    const ushort* a0 = A  + (size_t)(bm + r0) * K + kc;
    const ushort* a1 = A  + (size_t)(bm + r0 + 16) * K + kc;
    const ushort* b0 = BT + (size_t)(bn + r0) * K + kc;
    const ushort* b1 = BT + (size_t)(bn + r0 + 16) * K + kc;
    ushort* lA0 = lA + wave * 1024;
    ushort* lA1 = lA0 + 512;
    ushort* lB0 = lB + wave * 1024;
    ushort* lB1 = lB0 + 512;

    const int fr = lane & 15;
    const int kh = (lane >> 4) * 8;
    const ushort* ra = lA + (wr * 64 + fr) * 32 + kh;
    const ushort* rb = lB + (wc * 64 + fr) * 32 + kh;

    f32x4 acc[4][4] = {};

    for (int k0 = 0; k0 < K; k0 += 32) {
        GLD16(a0 + k0, lA0);
        GLD16(a1 + k0, lA1);
        GLD16(b0 + k0, lB0);
        GLD16(b1 + k0, lB1);
        asm volatile("s_waitcnt vmcnt(0)" ::: "memory");
        __syncthreads();
        bf16x8 af[4], bfr[4];
        #pragma unroll
        for (int m = 0; m < 4; ++m) af[m]  = *(const bf16x8*)(ra + m * 512);
        #pragma unroll
        for (int n = 0; n < 4; ++n) bfr[n] = *(const bf16x8*)(rb + n * 512);
        #pragma unroll
        for (int m = 0; m < 4; ++m)
            #pragma unroll
            for (int n = 0; n < 4; ++n)
                acc[m][n] = __builtin_amdgcn_mfma_f32_16x16x32_bf16(
                    af[m], bfr[n], acc[m][n], 0, 0, 0);
        __syncthreads();
    }

    const int orow = (lane >> 4) * 4;
    #pragma unroll
    for (int m = 0; m < 4; ++m)
        #pragma unroll
        for (int n = 0; n < 4; ++n) {
            float* dst = C + (size_t)(bm + wr * 64 + m * 16 + orow) * N
                           + bn + wc * 64 + n * 16 + fr;
            #pragma unroll
            for (int q = 0; q < 4; ++q)
                dst[(size_t)q * N] = acc[m][n][q];
        }
}

// ---------------------------------------------------------------------------
// Fused masked rotation + bf16 pack (SCALE folded into Qb).
// ---------------------------------------------------------------------------
__global__ __launch_bounds__(256)
void rotate_pack_qk(const float* __restrict__ t1, const int* __restrict__ mask,
                    const float* __restrict__ rot, ushort* __restrict__ Qb,
                    ushort* __restrict__ Kb)
{
    const int p   = blockIdx.x;
    const int tid = threadIdx.x;
    const int b = p >> 10, s = p & 1023;
    const bool rotated = (mask[p] != 0);   // block-uniform

    __shared__ float R[64][69];
    __shared__ float qv[QKD];
    __shared__ float kv[QKD];

    const float* tq = t1 + (size_t)p * 1024;
    {
        float2 q2 = *(const float2*)(tq + tid*2);
        float2 k2 = *(const float2*)(tq + QKD + tid*2);
        qv[tid*2]   = q2.x; qv[tid*2+1] = q2.y;
        kv[tid*2]   = k2.x; kv[tid*2+1] = k2.y;
        if (rotated) {
            const float* Rg = rot + (size_t)p * 4096;
            const int base = tid * 16;
            const int r = base >> 6, c = base & 63;
            #pragma unroll
            for (int x = 0; x < 16; x += 4) {
                float4 v = *(const float4*)(Rg + base + x);
                R[r][c+x+0] = v.x; R[r][c+x+1] = v.y;
                R[r][c+x+2] = v.z; R[r][c+x+3] = v.w;
            }
        }
    }
    __syncthreads();

    #pragma unroll
    for (int ph = 0; ph < 2; ++ph) {
        const int h = (tid >> 6) + ph*4;
        const int i = tid & 63;
        const float* qh  = &qv[h*64];
        const float* kh2 = &kv[h*64];
        float aq, ak;
        if (rotated) {
            aq = 0.f; ak = 0.f;
            #pragma unroll 8
            for (int j = 0; j < 64; ++j) {
                aq = fmaf(R[i][j], qh[j], aq);    // (R q)_i
                ak = fmaf(R[j][i], kh2[j], ak);   // (R^T k)_i
            }
        } else {
            aq = qh[i]; ak = kh2[i];
        }
        const size_t dst = ((size_t)(b*NH + h)*SEQ + s)*HD + i;
        Qb[dst] = f2bf(aq * SCALE);               // exact pow2 scale
        Kb[dst] = f2bf(ak);
    }
}

// ---------------------------------------------------------------------------
// MFMA Taylor attention, swapped-QK^T P path.
// Block = (b*8+h, 64 q-rows), 4 waves x 16 q-rows, 1 barrier/iter.
// QK^T computed as mfma(K,Q) so each lane's 4 D-values are 4 consecutive
// KEYS of one q-row -> packed b64 P writes, b128 P reads, scalar denom.
// ---------------------------------------------------------------------------
__global__ __launch_bounds__(256, 2)
void taylor_attn_mfma(const ushort* __restrict__ Qb, const ushort* __restrict__ Kb,
                      const ushort* __restrict__ Vt, const int* __restrict__ mask,
                      ushort* __restrict__ attn)
{
    const int bh  = blockIdx.x;
    const int qt  = blockIdx.y;
    const int b   = bh >> 3, h = bh & 7;
    const int tid = threadIdx.x;
    const int lane = tid & 63;
    const int wave = tid >> 6;
    const int l15 = lane & 15;
    const int l4  = lane >> 4;

    __shared__ __align__(16) ushort Ks[2][64*64];    // [key][d], src-perm swizzled
    __shared__ __align__(16) ushort Vs[2][128*64];   // [vd][key], src-perm swizzled
    __shared__ __align__(16) ushort Ps[4][16*64];    // per-wave [q][key], swizzled
    __shared__ float mskAll[SEQ];

    // stage whole-seq mask once
    {
        int4 mv = *(const int4*)(mask + b*SEQ + tid*4);
        float4 f = make_float4(mv.x ? 1.f : 0.f, mv.y ? 1.f : 0.f,
                               mv.z ? 1.f : 0.f, mv.w ? 1.f : 0.f);
        *(float4*)&mskAll[tid*4] = f;
    }

    // Q fragments (pre-scaled by SCALE at pack time)
    const ushort* qrow = Qb + ((size_t)bh*SEQ + qt*64 + wave*16 + l15) * HD;
    bf16x8 qf0 = *(const bf16x8*)(qrow + l4*8);
    bf16x8 qf1 = *(const bf16x8*)(qrow + 32 + l4*8);

    // GLD16 per-lane pre-swizzled source pointers (dest linear, read swizzled)
    const int sub  = lane >> 3;                 // row-within-8 == row&7
    const int scol = ((lane & 7) * 8) ^ (sub << 3);
    const ushort* kp0 = Kb + (size_t)bh*SEQ*HD + (size_t)(8*(wave*2+0) + sub)*HD + scol;
    const ushort* kp1 = Kb + (size_t)bh*SEQ*HD + (size_t)(8*(wave*2+1) + sub)*HD + scol;
    const ushort* vp0 = Vt + (size_t)bh*VDD*SEQ + (size_t)(8*(wave*4+0) + sub)*SEQ + scol;
    const ushort* vp1 = Vt + (size_t)bh*VDD*SEQ + (size_t)(8*(wave*4+1) + sub)*SEQ + scol;
    const ushort* vp2 = Vt + (size_t)bh*VDD*SEQ + (size_t)(8*(wave*4+2) + sub)*SEQ + scol;
    const ushort* vp3 = Vt + (size_t)bh*VDD*SEQ + (size_t)(8*(wave*4+3) + sub)*SEQ + scol;

#define ISSUE_TILE(buf, ktn) do {                                          \
    GLD16(kp0 + (size_t)(ktn)*4096, &Ks[buf][(wave*2+0)*512]);             \
    GLD16(kp1 + (size_t)(ktn)*4096, &Ks[buf][(wave*2+1)*512]);             \
    GLD16(vp0 + (size_t)(ktn)*64,   &Vs[buf][(wave*4+0)*512]);             \
    GLD16(vp1 + (size_t)(ktn)*64,   &Vs[buf][(wave*4+1)*512]);             \
    GLD16(vp2 + (size_t)(ktn)*64,   &Vs[buf][(wave*4+2)*512]);             \
    GLD16(vp3 + (size_t)(ktn)*64,   &Vs[buf][(wave*4+3)*512]);             \
} while (0)

    f32x4 oacc[8] = {};
    float dacc[4] = {};          // per-nf denominator partials (q = l15)

    ISSUE_TILE(0, 0);

    for (int kt = 0; kt < 16; ++kt) {
        const int cur = kt & 1;
        asm volatile("s_waitcnt vmcnt(0)" ::: "memory");
        __syncthreads();
        if (kt < 15) ISSUE_TILE(cur ^ 1, kt + 1);

        // ---- QK^T (swapped): sf[nf] = S^T block, rows=key, col=q=l15 ----
        f32x4 sf[4] = {};
        __builtin_amdgcn_s_setprio(1);
        #pragma unroll
        for (int nf = 0; nf < 4; ++nf) {
            const int row = nf*16 + l15;
            bf16x8 kf0 = *(const bf16x8*)&Ks[cur][SW(row, l4*8)];
            bf16x8 kf1 = *(const bf16x8*)&Ks[cur][SW(row, 32 + l4*8)];
            sf[nf] = __builtin_amdgcn_mfma_f32_16x16x32_bf16(kf0, qf0, sf[nf], 0, 0, 0);
            sf[nf] = __builtin_amdgcn_mfma_f32_16x16x32_bf16(kf1, qf1, sf[nf], 0, 0, 0);
        }
        __builtin_amdgcn_s_setprio(0);

        // ---- transform: 4 consecutive keys per lane -> packed P write ----
        #pragma unroll
        for (int nf = 0; nf < 4; ++nf) {
            const float4 mq = *(const float4*)&mskAll[kt*64 + nf*16 + l4*4];
            float sc0, sc1, sc2, sc3;
            {
                const float s = sf[nf][0];
                sc0 = fmaf(fmaf(0.5f*s, s, s), mq.x, mq.x);   // (1+s+s^2/2)*m
            }
            {
                const float s = sf[nf][1];
                sc1 = fmaf(fmaf(0.5f*s, s, s), mq.y, mq.y);
            }
            {
                const float s = sf[nf][2];
                sc2 = fmaf(fmaf(0.5f*s, s, s), mq.z, mq.z);
            }
            {
                const float s = sf[nf][3];
                sc3 = fmaf(fmaf(0.5f*s, s, s), mq.w, mq.w);
            }
            dacc[nf] += (sc0 + sc1) + (sc2 + sc3);
            ushort p4[4];
            p4[0] = (ushort)__builtin_bit_cast(unsigned short, (__bf16)sc0);
            p4[1] = (ushort)__builtin_bit_cast(unsigned short, (__bf16)sc1);
            p4[2] = (ushort)__builtin_bit_cast(unsigned short, (__bf16)sc2);
            p4[3] = (ushort)__builtin_bit_cast(unsigned short, (__bf16)sc3);
            // Ps[wave][q=l15][keys nf*16+l4*4 .. +4), swizzled by q
            const int col = (nf*16 + l4*4) ^ ((l15 & 7) << 3);
            *(ushort4*)&Ps[wave][l15*64 + col] = *(ushort4*)p4;
        }

        // ---- PV: A = P[q][k] (b128 reads, layout matches by construction) ----
        __builtin_amdgcn_s_setprio(1);
        #pragma unroll
        for (int ks = 0; ks < 2; ++ks) {
            const int pcol = (ks*32 + l4*8) ^ ((l15 & 7) << 3);
            bf16x8 pa = *(const bf16x8*)&Ps[wave][l15*64 + pcol];
            #pragma unroll
            for (int nf = 0; nf < 8; ++nf) {
                bf16x8 vf = *(const bf16x8*)&Vs[cur][SW(nf*16 + l15, ks*32 + l4*8)];
                oacc[nf] = __builtin_amdgcn_mfma_f32_16x16x32_bf16(pa, vf, oacc[nf], 0, 0, 0);
            }
        }
        __builtin_amdgcn_s_setprio(0);
    }
#undef ISSUE_TILE

    // ---- denominator: per-lane scalar (q=l15); reduce over l4 groups ----
    float d = (dacc[0] + dacc[1]) + (dacc[2] + dacc[3]);
    d += __shfl_xor(d, 16);
    d += __shfl_xor(d, 32);
    // redistribute: lane needs denom for q = l4*4 + rg
    float inv[4];
    #pragma unroll
    for (int rg = 0; rg < 4; ++rg)
        inv[rg] = 1.f / fmaxf(__shfl(d, l4*4 + rg), 1e-6f);

    ushort* orow = attn + ((size_t)(b*SEQ + qt*64 + wave*16 + l4*4)) * DIMX
                 + h*VDD + l15;
    #pragma unroll
    for (int nf = 0; nf < 8; ++nf)
        #pragma unroll
        for (int rg = 0; rg < 4; ++rg)
            orow[(size_t)rg*DIMX + nf*16] = f2bf(oacc[nf][rg] * inv[rg]);
}

// ---------------------------------------------------------------------------
extern "C" void kernel_launch(void* const* d_in, const int* in_sizes, int n_in,
                              void* d_out, int out_size, void* d_ws, size_t ws_size,
                              hipStream_t stream)
{
    const float* x    = (const float*)d_in[0];
    const int*   mask = (const int*)d_in[1];
    const float* rot  = (const float*)d_in[2];
    const float* w_t  = (const float*)d_in[3];
    const float* w_o  = (const float*)d_in[4];
    float* out = (float*)d_out;

    // workspace (46 MB):
    // t1 16MB | xbf/attnbf 8MB | wtT 4MB | woT 2MB | Qb 4MB | Kb 4MB | Vt 8MB
    float*  t1     = (float*)d_ws;
    ushort* xbf    = (ushort*)(t1 + (size_t)NPOS * 1024);
    ushort* attnbf = xbf;                            // xbf dead after gemm_qkv
    ushort* wtT    = xbf + (size_t)NPOS * DIMX;
    ushort* woT    = wtT + (size_t)TW * DIMX;
    ushort* Qb     = woT + (size_t)DIMX * DIMX;
    ushort* Kb     = Qb  + (size_t)BATCH * NH * SEQ * HD;
    ushort* Vtp    = Kb  + (size_t)BATCH * NH * SEQ * HD;

    // 0) precision conversions
    cast_bf16<<<(NPOS*DIMX/4 + 255)/256, 256, 0, stream>>>(x, xbf, NPOS*DIMX/4);
    transpose_cast<<<dim3(TW/32, DIMX/32),   256, 0, stream>>>(w_t, wtT, DIMX, TW);
    transpose_cast<<<dim3(DIMX/32, DIMX/32), 256, 0, stream>>>(w_o, woT, DIMX, DIMX);

    // 1) qkv projection: q,k -> t1 fp32; v -> Vt bf16 (transposed per head)
    gemm_qkv<<<dim3(TW/128, NPOS/128), 256, 0, stream>>>(xbf, wtT, t1, Vtp);
    // 2) fused masked rotation + bf16 pack (Q pre-scaled) -> Qb, Kb
    rotate_pack_qk<<<NPOS, 256, 0, stream>>>(t1, mask, rot, Qb, Kb);
    // 3) fused MFMA Taylor attention -> attnbf [NPOS, DIMX] bf16
    taylor_attn_mfma<<<dim3(BATCH*NH, SEQ/64), 256, 0, stream>>>(Qb, Kb, Vtp, mask, attnbf);
    // 4) out = attn @ w_o
    gemm_bf16_mfma<<<dim3(DIMX/128, NPOS/128), 256, 0, stream>>>(attnbf, woT, out, NPOS, DIMX, DIMX);
}